// Round 1
// baseline (571.280 us; speedup 1.0000x reference)
//
#include <hip/hip_runtime.h>
#include <math.h>

// Problem constants
#define BATCH 16
#define CH    64
#define HDIM  256
#define WDIM  256
#define HW    65536        // 256*256
#define KS    7
#define HIDN  16
#define COUT  3136         // CH * KS * KS
#define NPLANE 1024        // BATCH * CH

// ---------------------------------------------------------------------------
// Kernel 1: global average pool. One block per (b,c) plane; 512 threads each
// read 32 float4 (contiguous, coalesced), wave shuffle-reduce, LDS combine.
// ---------------------------------------------------------------------------
__global__ __launch_bounds__(512) void gap_kernel(const float* __restrict__ x,
                                                  float* __restrict__ pooled) {
    const int p = blockIdx.x;
    const float4* xv = (const float4*)(x + (size_t)p * HW);
    const int t = threadIdx.x;
    float s = 0.f;
    // 16384 float4 per plane / 512 threads = 32 iters
    #pragma unroll 4
    for (int i = t; i < 16384; i += 512) {
        float4 a = xv[i];
        s += (a.x + a.y) + (a.z + a.w);
    }
    // wave (64-lane) reduction
    #pragma unroll
    for (int off = 32; off > 0; off >>= 1) s += __shfl_down(s, off);
    __shared__ float sp[8];
    const int wid = t >> 6, lane = t & 63;
    if (lane == 0) sp[wid] = s;
    __syncthreads();
    if (t == 0) {
        float tot = 0.f;
        #pragma unroll
        for (int i = 0; i < 8; ++i) tot += sp[i];
        pooled[p] = tot * (1.0f / 65536.0f);
    }
}

// ---------------------------------------------------------------------------
// Kernel 2: MLP weight generator.
//   hdn = gelu_exact(pooled @ w1 + b1)        (16,64)@(64,16) -> (16,16)
//   wts = sigmoid(hdn @ w2 + b2)              (16,16)@(16,3136) -> (16,3136)
// 196 blocks x 256 threads; every block redundantly computes hdn (trivial),
// each thread produces one of the 50176 outputs.
// ---------------------------------------------------------------------------
__global__ __launch_bounds__(256) void mlp_kernel(const float* __restrict__ pooled,
                                                  const float* __restrict__ w1,
                                                  const float* __restrict__ b1,
                                                  const float* __restrict__ w2,
                                                  const float* __restrict__ b2,
                                                  float* __restrict__ wout) {
    __shared__ float s_pool[NPLANE];
    __shared__ float s_hdn[BATCH * HIDN];
    const int t = threadIdx.x;
    for (int i = t; i < NPLANE; i += 256) s_pool[i] = pooled[i];
    __syncthreads();
    {
        const int i = t >> 4, j = t & 15;   // 256 threads = all 16x16 hdn entries
        float acc = b1[j];
        #pragma unroll
        for (int c = 0; c < 64; ++c) acc += s_pool[i * 64 + c] * w1[c * HIDN + j];
        // exact GELU: 0.5*x*(1+erf(x/sqrt(2)))
        s_hdn[t] = 0.5f * acc * (1.0f + erff(acc * 0.70710678118654752f));
    }
    __syncthreads();
    const int o = blockIdx.x * 256 + t;     // < 50176
    const int i = o / COUT;
    const int j = o - i * COUT;
    float acc = b2[j];
    #pragma unroll
    for (int h = 0; h < HIDN; ++h) acc += s_hdn[i * HIDN + h] * w2[h * COUT + j];
    wout[o] = 1.0f / (1.0f + expf(-acc));
}

// ---------------------------------------------------------------------------
// Kernel 3: depthwise 7x7 conv with reflect padding, dynamic per-plane weights.
// 64x64 output tile per block (grid 4x4x1024), 256 threads.
// LDS stages the 70x70 input halo tile (stride 72 => 16B-aligned rows).
// Each thread computes a 4-wide x 4-tall register block via a vertical
// sliding window: 10 input rows, 3 ds_read_b128 per row, 784 FMAs.
// ---------------------------------------------------------------------------
#define TILE 64
#define INT  70            // TILE + 6
#define LDSS 72            // padded LDS row stride (floats), 288B => 16B aligned

__global__ __launch_bounds__(256) void conv_kernel(const float* __restrict__ x,
                                                   const float* __restrict__ wts,
                                                   float* __restrict__ out) {
    __shared__ float s_in[INT * LDSS];
    __shared__ float s_w[49];
    const int p = blockIdx.z;
    const size_t pbase = (size_t)p * HW;
    const int gx0 = blockIdx.x * TILE - 3;
    const int gy0 = blockIdx.y * TILE - 3;
    const int t = threadIdx.x;

    if (t < 49) s_w[t] = wts[p * 49 + t];

    // stage 70x70 input tile with reflect indexing
    for (int idx = t; idx < INT * INT; idx += 256) {
        const int r = idx / INT;
        const int c = idx - r * INT;
        int gy = gy0 + r;
        gy = gy < 0 ? -gy : (gy > 255 ? 510 - gy : gy);
        int gx = gx0 + c;
        gx = gx < 0 ? -gx : (gx > 255 ? 510 - gx : gx);
        s_in[r * LDSS + c] = x[pbase + (size_t)gy * WDIM + gx];
    }
    __syncthreads();

    float w[49];
    #pragma unroll
    for (int i = 0; i < 49; ++i) w[i] = s_w[i];

    const int tx4 = (t & 15) * 4;        // output col within tile (0..60)
    const int ty  = (t >> 4) * 4;        // output row within tile (0..60)

    float acc[16];
    #pragma unroll
    for (int i = 0; i < 16; ++i) acc[i] = 0.f;

    #pragma unroll
    for (int r = 0; r < 10; ++r) {
        const float* rp = &s_in[(ty + r) * LDSS + tx4];
        const float4 v0 = *(const float4*)(rp);
        const float4 v1 = *(const float4*)(rp + 4);
        const float4 v2 = *(const float4*)(rp + 8);
        const float row[12] = {v0.x, v0.y, v0.z, v0.w,
                               v1.x, v1.y, v1.z, v1.w,
                               v2.x, v2.y, v2.z, v2.w};
        #pragma unroll
        for (int o = 0; o < 4; ++o) {
            const int ky = r - o;
            if (ky < 0 || ky > 6) continue;      // compile-time resolved
            #pragma unroll
            for (int kx = 0; kx < 7; ++kx) {
                const float wv = w[ky * 7 + kx];
                acc[o * 4 + 0] += wv * row[kx + 0];
                acc[o * 4 + 1] += wv * row[kx + 1];
                acc[o * 4 + 2] += wv * row[kx + 2];
                acc[o * 4 + 3] += wv * row[kx + 3];
            }
        }
    }

    const int oy0 = blockIdx.y * TILE + ty;
    const int ox  = blockIdx.x * TILE + tx4;
    #pragma unroll
    for (int o = 0; o < 4; ++o) {
        const float4 v = make_float4(acc[o * 4 + 0], acc[o * 4 + 1],
                                     acc[o * 4 + 2], acc[o * 4 + 3]);
        *(float4*)&out[pbase + (size_t)(oy0 + o) * WDIM + ox] = v;
    }
}

// ---------------------------------------------------------------------------
extern "C" void kernel_launch(void* const* d_in, const int* in_sizes, int n_in,
                              void* d_out, int out_size, void* d_ws, size_t ws_size,
                              hipStream_t stream) {
    const float* x  = (const float*)d_in[0];
    const float* w1 = (const float*)d_in[1];
    const float* b1 = (const float*)d_in[2];
    const float* w2 = (const float*)d_in[3];
    const float* b2 = (const float*)d_in[4];
    float* out = (float*)d_out;

    float* pooled = (float*)d_ws;           // 1024 floats
    float* wts    = pooled + NPLANE;        // 50176 floats

    gap_kernel<<<NPLANE, 512, 0, stream>>>(x, pooled);
    mlp_kernel<<<(BATCH * COUT) / 256, 256, 0, stream>>>(pooled, w1, b1, w2, b2, wts);
    conv_kernel<<<dim3(WDIM / TILE, HDIM / TILE, NPLANE), 256, 0, stream>>>(x, wts, out);
}

// Round 2
// 568.531 us; speedup vs baseline: 1.0048x; 1.0048x over previous
//
#include <hip/hip_runtime.h>
#include <math.h>

// Problem constants
#define BATCH 16
#define CH    64
#define HDIM  256
#define WDIM  256
#define HW    65536        // 256*256
#define KS    7
#define HIDN  16
#define COUT  3136         // CH * KS * KS
#define NPLANE 1024        // BATCH * CH

// ---------------------------------------------------------------------------
// Kernel 1: global average pool. One block per (b,c) plane; 512 threads each
// read 32 float4 (contiguous, coalesced), wave shuffle-reduce, LDS combine.
// ---------------------------------------------------------------------------
__global__ __launch_bounds__(512) void gap_kernel(const float* __restrict__ x,
                                                  float* __restrict__ pooled) {
    const int p = blockIdx.x;
    const float4* xv = (const float4*)(x + (size_t)p * HW);
    const int t = threadIdx.x;
    float s = 0.f;
    #pragma unroll 4
    for (int i = t; i < 16384; i += 512) {
        float4 a = xv[i];
        s += (a.x + a.y) + (a.z + a.w);
    }
    #pragma unroll
    for (int off = 32; off > 0; off >>= 1) s += __shfl_down(s, off);
    __shared__ float sp[8];
    const int wid = t >> 6, lane = t & 63;
    if (lane == 0) sp[wid] = s;
    __syncthreads();
    if (t == 0) {
        float tot = 0.f;
        #pragma unroll
        for (int i = 0; i < 8; ++i) tot += sp[i];
        pooled[p] = tot * (1.0f / 65536.0f);
    }
}

// ---------------------------------------------------------------------------
// Kernel 2: MLP weight generator (hdn = gelu(pooled@w1+b1); wts = sigmoid(hdn@w2+b2))
// ---------------------------------------------------------------------------
__global__ __launch_bounds__(256) void mlp_kernel(const float* __restrict__ pooled,
                                                  const float* __restrict__ w1,
                                                  const float* __restrict__ b1,
                                                  const float* __restrict__ w2,
                                                  const float* __restrict__ b2,
                                                  float* __restrict__ wout) {
    __shared__ float s_pool[NPLANE];
    __shared__ float s_hdn[BATCH * HIDN];
    const int t = threadIdx.x;
    for (int i = t; i < NPLANE; i += 256) s_pool[i] = pooled[i];
    __syncthreads();
    {
        const int i = t >> 4, j = t & 15;
        float acc = b1[j];
        #pragma unroll
        for (int c = 0; c < 64; ++c) acc += s_pool[i * 64 + c] * w1[c * HIDN + j];
        s_hdn[t] = 0.5f * acc * (1.0f + erff(acc * 0.70710678118654752f));
    }
    __syncthreads();
    const int o = blockIdx.x * 256 + t;
    const int i = o / COUT;
    const int j = o - i * COUT;
    float acc = b2[j];
    #pragma unroll
    for (int h = 0; h < HIDN; ++h) acc += s_hdn[i * HIDN + h] * w2[h * COUT + j];
    wout[o] = 1.0f / (1.0f + expf(-acc));
}

// ---------------------------------------------------------------------------
// Kernel 3: depthwise 7x7 conv, reflect pad, dynamic per-plane weights.
// Tile 128 wide x 64 tall per block (grid 2x4x1024), 256 threads.
// Thread layout: 32 lanes span a full 128-wide row (consecutive float4 =>
// conflict-free ds_read_b128 in any phase split); each thread computes a
// 4-wide x 8-tall register block via a vertical sliding window.
// LDS: 70 rows x 136-float stride (134 used, 16B-aligned). 49 weights held
// in VGPRs (launch_bounds(256,3) => up to ~168 VGPRs).
// ---------------------------------------------------------------------------
#define TLX 128
#define TLY 64
#define INX 134            // TLX + 6
#define INY 70             // TLY + 6
#define LDSS 136           // padded LDS row stride (floats), 544B, 16B-aligned

__global__ __launch_bounds__(256, 3) void conv_kernel(const float* __restrict__ x,
                                                      const float* __restrict__ wts,
                                                      float* __restrict__ out) {
    __shared__ float s_in[INY * LDSS];
    __shared__ float s_w[49];
    const int p = blockIdx.z;
    const size_t pbase = (size_t)p * HW;
    const int gx0 = blockIdx.x * TLX - 3;
    const int gy0 = blockIdx.y * TLY - 3;
    const int t = threadIdx.x;

    if (t < 49) s_w[t] = wts[p * 49 + t];

    // stage 70x134 input tile with reflect indexing (coalesced: consecutive
    // threads -> consecutive gx)
    for (int idx = t; idx < INY * INX; idx += 256) {
        const int r = idx / INX;
        const int c = idx - r * INX;
        int gy = gy0 + r;
        gy = gy < 0 ? -gy : (gy > 255 ? 510 - gy : gy);
        int gx = gx0 + c;
        gx = gx < 0 ? -gx : (gx > 255 ? 510 - gx : gx);
        s_in[r * LDSS + c] = x[pbase + (size_t)gy * WDIM + gx];
    }
    __syncthreads();

    float w[49];
    #pragma unroll
    for (int i = 0; i < 49; ++i) w[i] = s_w[i];

    const int tx4 = (t & 31) * 4;        // output col within tile (0..124)
    const int ty  = (t >> 5) * 8;        // output row within tile (0..56)

    float acc[32];
    #pragma unroll
    for (int i = 0; i < 32; ++i) acc[i] = 0.f;

    // vertical sliding window over 14 input rows -> 8 output rows
    #pragma unroll
    for (int r = 0; r < 14; ++r) {
        const float* rp = &s_in[(ty + r) * LDSS + tx4];
        const float4 v0 = *(const float4*)(rp);
        const float4 v1 = *(const float4*)(rp + 4);
        const float4 v2 = *(const float4*)(rp + 8);
        const float row[12] = {v0.x, v0.y, v0.z, v0.w,
                               v1.x, v1.y, v1.z, v1.w,
                               v2.x, v2.y, v2.z, v2.w};
        #pragma unroll
        for (int o = 0; o < 8; ++o) {
            const int ky = r - o;
            if (ky < 0 || ky > 6) continue;      // compile-time resolved
            #pragma unroll
            for (int kx = 0; kx < 7; ++kx) {
                const float wv = w[ky * 7 + kx];
                acc[o * 4 + 0] += wv * row[kx + 0];
                acc[o * 4 + 1] += wv * row[kx + 1];
                acc[o * 4 + 2] += wv * row[kx + 2];
                acc[o * 4 + 3] += wv * row[kx + 3];
            }
        }
    }

    const int oy0 = blockIdx.y * TLY + ty;
    const int ox  = blockIdx.x * TLX + tx4;
    #pragma unroll
    for (int o = 0; o < 8; ++o) {
        const float4 v = make_float4(acc[o * 4 + 0], acc[o * 4 + 1],
                                     acc[o * 4 + 2], acc[o * 4 + 3]);
        *(float4*)&out[pbase + (size_t)(oy0 + o) * WDIM + ox] = v;
    }
}

// ---------------------------------------------------------------------------
extern "C" void kernel_launch(void* const* d_in, const int* in_sizes, int n_in,
                              void* d_out, int out_size, void* d_ws, size_t ws_size,
                              hipStream_t stream) {
    const float* x  = (const float*)d_in[0];
    const float* w1 = (const float*)d_in[1];
    const float* b1 = (const float*)d_in[2];
    const float* w2 = (const float*)d_in[3];
    const float* b2 = (const float*)d_in[4];
    float* out = (float*)d_out;

    float* pooled = (float*)d_ws;           // 1024 floats
    float* wts    = pooled + NPLANE;        // 50176 floats

    gap_kernel<<<NPLANE, 512, 0, stream>>>(x, pooled);
    mlp_kernel<<<(BATCH * COUT) / 256, 256, 0, stream>>>(pooled, w1, b1, w2, b2, wts);
    conv_kernel<<<dim3(WDIM / TLX, HDIM / TLY, NPLANE), 256, 0, stream>>>(x, wts, out);
}